// Round 6
// baseline (325.796 us; speedup 1.0000x reference)
//
#include <hip/hip_runtime.h>

// (B,H,Lq,Lkv) = (2,32,2048,2048), KEEP_RATIO=0.5, SINK=4, RECENT=64, ALPHA=0.2
#define B_   2
#define H_   32
#define BH   64
#define LQ   2048
#define LKV  2048
#define SINKN   4
#define RECENTN 64
#define MID  1980                              // LKV - SINK - RECENT
#define TOTAL_BUDGET 30592                     // (1024-68)*32
#define MINB 198                               // int(1980*0.5*0.2)
#define QCH  32
#define QLEN 64                                // LQ/QCH rows per stats block
#define ICH  4
#define ILEN 495                               // MID/ICH

// Native v_log_f32 (log2, ~2^-21 rel err).
static __device__ __forceinline__ float fast_log2(float x) {
#if defined(__has_builtin) && __has_builtin(__builtin_amdgcn_logf)
  return __builtin_amdgcn_logf(x);
#else
  float r; asm volatile("v_log_f32 %0, %1" : "=v"(r) : "v"(x)); return r;
#endif
}

// Streaming pass, m13-like occupancy: 2048 blocks x 256 thr, each block one
// contiguous 512KB slab (64 rows). f32 group-of-4-rows accumulation folded
// into f64 (fixed order -> deterministic). Entropy = sum(w*log2(w+eps)),
// scaled by -ln2 in budget_kernel.
__global__ __launch_bounds__(256) void stats_kernel(const float* __restrict__ A,
                                                    double* __restrict__ spart,
                                                    double* __restrict__ epart) {
  const int qc = blockIdx.x;      // 0..QCH-1
  const int bh = blockIdx.y;      // 0..63
  const int t  = threadIdx.x;     // 0..255
  const float4* __restrict__ p = reinterpret_cast<const float4*>(
      A + ((size_t)bh * LQ + (size_t)qc * QLEN) * LKV);

  double s0=0,s1=0,s2=0,s3=0,s4=0,s5=0,s6=0,s7=0,e=0;
  for (int g = 0; g < QLEN; g += 4) {
    float a0=0.f,a1=0.f,a2=0.f,a3=0.f,b0=0.f,b1=0.f,b2=0.f,b3=0.f,e0=0.f,e1=0.f;
#pragma unroll
    for (int r = 0; r < 4; ++r) {
      float4 w = p[(size_t)(g + r) * 512 + t];
      float4 v = p[(size_t)(g + r) * 512 + 256 + t];
      a0 += w.x; a1 += w.y; a2 += w.z; a3 += w.w;
      e0 = fmaf(w.x, fast_log2(w.x + 1e-8f), e0);
      e0 = fmaf(w.y, fast_log2(w.y + 1e-8f), e0);
      e0 = fmaf(w.z, fast_log2(w.z + 1e-8f), e0);
      e0 = fmaf(w.w, fast_log2(w.w + 1e-8f), e0);
      b0 += v.x; b1 += v.y; b2 += v.z; b3 += v.w;
      e1 = fmaf(v.x, fast_log2(v.x + 1e-8f), e1);
      e1 = fmaf(v.y, fast_log2(v.y + 1e-8f), e1);
      e1 = fmaf(v.z, fast_log2(v.z + 1e-8f), e1);
      e1 = fmaf(v.w, fast_log2(v.w + 1e-8f), e1);
    }
    s0 += (double)a0; s1 += (double)a1; s2 += (double)a2; s3 += (double)a3;
    s4 += (double)b0; s5 += (double)b1; s6 += (double)b2; s7 += (double)b3;
    e += (double)e0 + (double)e1;
  }
  double* sp = spart + (size_t)(qc * BH + bh) * LKV;
  const int c0 = 4 * t, c1 = 1024 + 4 * t;
  sp[c0] = s0; sp[c0 + 1] = s1; sp[c0 + 2] = s2; sp[c0 + 3] = s3;
  sp[c1] = s4; sp[c1 + 1] = s5; sp[c1 + 2] = s6; sp[c1 + 3] = s7;

  __shared__ double red[256];
  red[t] = e;
  __syncthreads();
  for (int off = 128; off > 0; off >>= 1) {
    if (t < off) red[t] += red[t + off];
    __syncthreads();
  }
  if (t == 0) epart[(size_t)bh * QCH + qc] = red[0];
}

// Sum the QCH partials for the middle columns -> sfin[bh][MID] (f64, fixed order).
__global__ __launch_bounds__(256) void reduce_kernel(const double* __restrict__ spart,
                                                     double* __restrict__ sfin) {
  const int slice = blockIdx.x, bh = blockIdx.y, t = threadIdx.x;  // slice 0..3
#pragma unroll
  for (int m = 0; m < 2; ++m) {
    int lj = t + 256 * m;
    if (lj < ILEN) {
      int j = slice * ILEN + lj;
      double v = 0.0;
      for (int qc = 0; qc < QCH; ++qc)
        v += spart[(size_t)(qc * BH + bh) * LKV + SINKN + j];
      sfin[(size_t)bh * MID + j] = v;
    }
  }
}

// head_entropy -> budgets -> k per (b,h). Half-even rint, Python floor-div.
__global__ __launch_bounds__(64) void budget_kernel(const double* __restrict__ epart,
                                                    int* __restrict__ kvals) {
  __shared__ double he[BH];
  __shared__ int bud[H_];
  const int t = threadIdx.x;  // 0..63 = bh
  double s = 0.0;
  for (int p = 0; p < QCH; ++p) s += epart[(size_t)t * QCH + p];
  he[t] = (-0.6931471805599453 * s) / (double)LQ;
  __syncthreads();
  if (t == 0) {
    for (int b = 0; b < B_; ++b) {
      double S = 0.0;
      for (int h = 0; h < H_; ++h) S += he[b * H_ + h];
      S += 1e-8;
      long long sum = 0;
      for (int h = 0; h < H_; ++h) {
        double x = he[b * H_ + h] / S * (double)TOTAL_BUDGET;
        int v = (int)rint(x);
        if (v < MINB) v = MINB;
        bud[h] = v; sum += v;
      }
      long long diff = (long long)TOTAL_BUDGET - sum;
      long long ph = (diff >= 0) ? diff / H_ : -((-diff + H_ - 1) / H_);
      long long rem = diff - ph * H_;
      for (int h = 0; h < H_; ++h) {
        long long v = (long long)bud[h] + ph + ((h < rem) ? 1 : 0);
        if (v < 1) v = 1;
        if (v > MID) v = MID;
        kvals[b * H_ + h] = (int)v;
      }
    }
  }
}

// Partial stable-descending rank counts. Block (chunk c, bh): each thread holds
// 8 j-scores in REGISTERS; i-scan over the chunk uses broadcast-only LDS reads
// (same address across lanes -> conflict-free). cnt = #{i in chunk: s_i > s_j}
//                                               + #{i in chunk, i<j: s_i == s_j}.
__global__ __launch_bounds__(256) void count_kernel(const double* __restrict__ sfin,
                                                    unsigned* __restrict__ cntp) {
  const int c = blockIdx.x, bh = blockIdx.y, t = threadIdx.x;
  __shared__ double s[MID];
  for (int m = t; m < MID; m += 256) s[m] = sfin[(size_t)bh * MID + m];
  __syncthreads();
  double kj[8]; unsigned cnt[8]; int jj[8];
#pragma unroll
  for (int m = 0; m < 8; ++m) {
    jj[m] = t + 256 * m;
    kj[m] = (jj[m] < MID) ? s[jj[m]] : -1.0;
    cnt[m] = 0;
  }
  const int i0 = c * ILEN;
  for (int i = i0; i < i0 + ILEN; ++i) {
    const double si = s[i];
#pragma unroll
    for (int m = 0; m < 8; ++m) {
      cnt[m] += (si > kj[m]) ? 1u : 0u;
      cnt[m] += ((si == kj[m]) && (i < jj[m])) ? 1u : 0u;
    }
  }
#pragma unroll
  for (int m = 0; m < 8; ++m)
    if (jj[m] < MID) cntp[(size_t)(c * BH + bh) * MID + jj[m]] = cnt[m];
}

// Merge the ICH partial counts, threshold vs k, write int32 mask + protected.
__global__ __launch_bounds__(256) void final_kernel(const unsigned* __restrict__ cntp,
                                                    const int* __restrict__ kvals,
                                                    int* __restrict__ out) {
  const int bh = blockIdx.x, t = threadIdx.x;
  const unsigned k = (unsigned)kvals[bh];
#pragma unroll
  for (int m = 0; m < 8; ++m) {
    int j = t + 256 * m;
    if (j < MID) {
      unsigned r = 0;
      for (int c = 0; c < ICH; ++c) r += cntp[(size_t)(c * BH + bh) * MID + j];
      out[(size_t)bh * LKV + SINKN + j] = (r < k) ? 1 : 0;
    }
  }
  if (t < SINKN)   out[(size_t)bh * LKV + t] = 1;
  if (t < RECENTN) out[(size_t)bh * LKV + (LKV - RECENTN) + t] = 1;
}

extern "C" void kernel_launch(void* const* d_in, const int* in_sizes, int n_in,
                              void* d_out, int out_size, void* d_ws, size_t ws_size,
                              hipStream_t stream) {
  const float* A = (const float*)d_in[0];
  int* out = (int*)d_out;

  // ws layout: spart[QCH*64*2048 f64]=32MB | epart[64*QCH f64] | sfin[64*MID f64]
  //          | cntp[ICH*64*MID u32] | kvals[64 int]   (~37 MB total; ws is ~4GB)
  double* spart = (double*)d_ws;
  double* epart = spart + (size_t)QCH * BH * LKV;
  double* sfin  = epart + (size_t)BH * QCH;
  unsigned* cntp = (unsigned*)(sfin + (size_t)BH * MID);
  int* kvals = (int*)(cntp + (size_t)ICH * BH * MID);

  stats_kernel<<<dim3(QCH, BH), 256, 0, stream>>>(A, spart, epart);
  reduce_kernel<<<dim3(ICH, BH), 256, 0, stream>>>(spart, sfin);
  budget_kernel<<<1, 64, 0, stream>>>(epart, kvals);
  count_kernel<<<dim3(ICH, BH), 256, 0, stream>>>(sfin, cntp);
  final_kernel<<<BH, 256, 0, stream>>>(cntp, kvals, out);
}